// Round 3
// baseline (402.232 us; speedup 1.0000x reference)
//
#include <hip/hip_runtime.h>

#define TOKENS 90112
#define DM 256
#define NOUT 768
#define JOINTS 22

typedef __attribute__((ext_vector_type(8))) short bf16x8;
typedef __attribute__((ext_vector_type(4))) float f32x4;

__device__ __forceinline__ float b2f(unsigned short u) {
    union { unsigned int i; float f; } x; x.i = ((unsigned int)u) << 16; return x.f;
}
__device__ __forceinline__ unsigned short f2b(float f) {
    union { float f; unsigned int u; } x; x.f = f;
    unsigned int r = x.u + 0x7FFFu + ((x.u >> 16) & 1u);
    return (unsigned short)(r >> 16);
}

// ws layout (all offsets 16B-aligned)
#define OFF_FLAG 0
#define OFF_PEWB 16
#define OFF_XCAN (16 + 22 * 768 * 4)                         // 67600
#define OFF_WCAN (OFF_XCAN + TOKENS * DM * 2)                // + 46,137,344
#define OFF_BCAN (OFF_WCAN + 3 * DM * DM * 2)                // + 393,216
#define OFF_QKV  (OFF_BCAN + 3 * DM * 2 * 2)                 // pad bias region to 3072B

// ---------------- probe: decide whether inputs are bf16-packed or fp32 ----------------
__global__ __launch_bounds__(64) void probe_kernel(const unsigned int* __restrict__ x,
                                                   int* __restrict__ flag)
{
    __shared__ int cnt;
    if (threadIdx.x == 0) cnt = 0;
    __syncthreads();
    int local = 0;
    for (int i = threadIdx.x; i < 1024; i += 64) {
        unsigned int m = (x[i] >> 7) & 0xFF;   // bf16-packed: low-half exponent; fp32: mantissa bits
        if (m >= 118 && m <= 132) ++local;
    }
    atomicAdd(&cnt, local);
    __syncthreads();
    if (threadIdx.x == 0) *flag = (cnt >= 512) ? 1 : 0;   // 1 = bf16 storage
}

// ---------------- convert any input to canonical bf16 ----------------
__global__ __launch_bounds__(256) void convert_kernel(const void* __restrict__ src,
                                                      unsigned short* __restrict__ dst,
                                                      int n, const int* __restrict__ flag)
{
    const int isbf = *flag;
    const int stride = gridDim.x * blockDim.x * 8;
    if (isbf) {
        for (int i = (blockIdx.x * blockDim.x + threadIdx.x) * 8; i < n; i += stride)
            *(uint4*)(dst + i) = *(const uint4*)((const unsigned short*)src + i);
    } else {
        for (int i = (blockIdx.x * blockDim.x + threadIdx.x) * 8; i < n; i += stride) {
            const float* s = (const float*)src + i;
            union { uint4 v; float f[4]; } a, b;
            a.v = *(const uint4*)(s);
            b.v = *(const uint4*)(s + 4);
            union { uint4 v; unsigned short u[8]; } o;
            #pragma unroll
            for (int k = 0; k < 4; ++k) { o.u[k] = f2b(a.f[k]); o.u[4 + k] = f2b(b.f[k]); }
            *(uint4*)(dst + i) = o.v;
        }
    }
}

// ---------------- PEWB[j,e] = bias[e] + sum_d pe[j,d] * W[e,d] ----------------
__global__ __launch_bounds__(256) void pewb_kernel(const unsigned short* __restrict__ wcan,
                                                   const unsigned short* __restrict__ bcan,
                                                   float* __restrict__ pewb)
{
    __shared__ float pe_s[DM];
    const int j   = blockIdx.x / 3;
    const int mat = blockIdx.x % 3;
    const int t = threadIdx.x;
    {
        int i = t >> 1;
        float div = __expf((float)(2 * i) * (-9.210340371976184f / 256.0f)); // -ln(10000)/256
        float ang = (float)j * div;
        pe_s[t] = (t & 1) ? cosf(ang) : sinf(ang);
    }
    __syncthreads();
    const unsigned short* w  = wcan + mat * (DM * DM);
    const unsigned short* bb = bcan + mat * DM;
    float acc = b2f(bb[t]);
    const unsigned short* wr = w + (size_t)t * DM;
    #pragma unroll 8
    for (int d = 0; d < DM; ++d) acc += pe_s[d] * b2f(wr[d]);
    pewb[j * NOUT + mat * DM + t] = acc;
}

// ---------------- QKV = x @ Wcat^T + PEWB[joint]  (bf16 MFMA GEMM) ----------------
#define BM 128
#define BN 128
#define BK 64
#define LDK 72

__global__ __launch_bounds__(256) void qkv_gemm(const unsigned short* __restrict__ xcan,
                                                const unsigned short* __restrict__ wcan,
                                                const float* __restrict__ pewb,
                                                unsigned short* __restrict__ qkv)
{
    __shared__ __align__(16) unsigned short As[BM * LDK];
    __shared__ __align__(16) unsigned short Bs[BN * LDK];
    __shared__ float pewb_s[JOINTS * BN];

    const int t  = threadIdx.x;
    const int m0 = blockIdx.x * BM;
    const int bn = blockIdx.y;
    const int n0 = bn * BN;
    const unsigned short* wsel = wcan + (bn >> 1) * (DM * DM);
    const int e_off = (bn & 1) * BN;

    for (int i = t; i < JOINTS * BN; i += 256) {
        int jj = i >> 7; int cc = i & 127;
        pewb_s[i] = pewb[jj * NOUT + n0 + cc];
    }

    const int lane = t & 63;
    const int wave = t >> 6;
    const int wm   = (wave & 1) * 64;
    const int wn   = (wave >> 1) * 64;
    const int lrow = lane & 15;
    const int quad = lane >> 4;

    f32x4 acc[4][4];
    #pragma unroll
    for (int mi = 0; mi < 4; ++mi)
        #pragma unroll
        for (int ni = 0; ni < 4; ++ni)
            acc[mi][ni] = (f32x4){0.f, 0.f, 0.f, 0.f};

    for (int k0 = 0; k0 < DM; k0 += BK) {
        if (k0) __syncthreads();
        #pragma unroll
        for (int i = 0; i < 4; ++i) {
            int c = t + i * 256;
            int row = c >> 3, col8 = c & 7;
            *(uint4*)(&As[row * LDK + col8 * 8]) =
                *(const uint4*)(&xcan[(size_t)(m0 + row) * DM + k0 + col8 * 8]);
            *(uint4*)(&Bs[row * LDK + col8 * 8]) =
                *(const uint4*)(&wsel[(size_t)(e_off + row) * DM + k0 + col8 * 8]);
        }
        __syncthreads();
        #pragma unroll
        for (int kk = 0; kk < BK; kk += 32) {
            bf16x8 a[4], b[4];
            #pragma unroll
            for (int mi = 0; mi < 4; ++mi)
                a[mi] = *(const bf16x8*)(&As[(wm + mi * 16 + lrow) * LDK + kk + quad * 8]);
            #pragma unroll
            for (int ni = 0; ni < 4; ++ni)
                b[ni] = *(const bf16x8*)(&Bs[(wn + ni * 16 + lrow) * LDK + kk + quad * 8]);
            #pragma unroll
            for (int mi = 0; mi < 4; ++mi)
                #pragma unroll
                for (int ni = 0; ni < 4; ++ni)
                    acc[mi][ni] = __builtin_amdgcn_mfma_f32_16x16x32_bf16(
                        a[mi], b[ni], acc[mi][ni], 0, 0, 0);
        }
    }

    #pragma unroll
    for (int mi = 0; mi < 4; ++mi) {
        #pragma unroll
        for (int r = 0; r < 4; ++r) {
            int row = wm + mi * 16 + quad * 4 + r;   // C row = (lane>>4)*4 + reg
            int token = m0 + row;
            int joint = token % JOINTS;              // 176 % 22 == 0
            const float* pw = &pewb_s[joint * BN];
            size_t obase = (size_t)token * NOUT + n0;
            #pragma unroll
            for (int ni = 0; ni < 4; ++ni) {
                int col = wn + ni * 16 + lrow;       // C col = lane&15
                qkv[obase + col] = f2b(acc[mi][ni][r] + pw[col]);
            }
        }
    }
}

// ---------------- block-diagonal attention, one block per (batch, frame) ----------------
#define HSTR 708

__global__ __launch_bounds__(256) void attn_kernel(const unsigned short* __restrict__ qkv,
                                                   void* __restrict__ outv,
                                                   const int* __restrict__ flag)
{
    __shared__ float smem[2 * 8 * HSTR];
    const int t  = threadIdx.x;
    const int tb = blockIdx.x * JOINTS;

    for (int i = t; i < JOINTS * 64; i += 256) {
        int j  = i >> 6;
        int rc = 32 + (i & 63);
        int e  = rc * 8;            // 256..760
        int mat = e >> 8;           // 1=K, 2=V
        int h  = (e >> 5) & 7;
        int d0 = e & 31;
        union { uint4 v; unsigned short u[8]; } r;
        r.v = *(const uint4*)(&qkv[(size_t)(tb + j) * NOUT + e]);
        float* dst = smem + (mat - 1) * (8 * HSTR) + h * HSTR + j * 32 + d0;
        #pragma unroll
        for (int ii = 0; ii < 8; ++ii) dst[ii] = b2f(r.u[ii]);
    }
    __syncthreads();

    if (t < 176) {
        const int h  = t / 22;
        const int qi = t - h * 22;
        const int token = tb + qi;

        float q[32];
        {
            const unsigned short* qg = qkv + (size_t)token * NOUT + h * 32;
            #pragma unroll
            for (int c4 = 0; c4 < 4; ++c4) {
                union { uint4 v; unsigned short u[8]; } r;
                r.v = *(const uint4*)(qg + c4 * 8);
                #pragma unroll
                for (int ii = 0; ii < 8; ++ii)
                    q[c4 * 8 + ii] = b2f(r.u[ii]) * 0.17677669529663688f; // 1/sqrt(32)
            }
        }
        const float* kh = smem + h * HSTR;
        const float* vh = smem + 8 * HSTR + h * HSTR;

        float sc[22];
        float mx = -3.0e38f;
        #pragma unroll
        for (int j = 0; j < 22; ++j) {
            const float* kr = kh + j * 32;
            float s = 0.f;
            #pragma unroll
            for (int d = 0; d < 32; ++d) s += q[d] * kr[d];
            sc[j] = s;
            mx = fmaxf(mx, s);
        }
        float sum = 0.f;
        #pragma unroll
        for (int j = 0; j < 22; ++j) { sc[j] = __expf(sc[j] - mx); sum += sc[j]; }
        float inv = 1.f / sum;

        float o[32];
        #pragma unroll
        for (int d = 0; d < 32; ++d) o[d] = 0.f;
        #pragma unroll
        for (int j = 0; j < 22; ++j) {
            float p = sc[j] * inv;
            const float* vr = vh + j * 32;
            #pragma unroll
            for (int d = 0; d < 32; ++d) o[d] += p * vr[d];
        }

        const int isbf = *flag;
        if (isbf) {
            unsigned int buf[16];
            #pragma unroll
            for (int i = 0; i < 16; ++i)
                buf[i] = (unsigned int)f2b(o[2 * i]) | ((unsigned int)f2b(o[2 * i + 1]) << 16);
            uint4* dst = (uint4*)((unsigned short*)outv + (size_t)token * DM + h * 32);
            #pragma unroll
            for (int i = 0; i < 4; ++i) dst[i] = ((uint4*)buf)[i];
        } else {
            float* dst = (float*)outv + (size_t)token * DM + h * 32;
            #pragma unroll
            for (int i = 0; i < 8; ++i)
                *(float4*)(dst + i * 4) = make_float4(o[i * 4], o[i * 4 + 1], o[i * 4 + 2], o[i * 4 + 3]);
        }
    }
}

extern "C" void kernel_launch(void* const* d_in, const int* in_sizes, int n_in,
                              void* d_out, int out_size, void* d_ws, size_t ws_size,
                              hipStream_t stream) {
    char* ws = (char*)d_ws;
    int*            flag = (int*)(ws + OFF_FLAG);
    float*          pewb = (float*)(ws + OFF_PEWB);
    unsigned short* xcan = (unsigned short*)(ws + OFF_XCAN);
    unsigned short* wcan = (unsigned short*)(ws + OFF_WCAN);
    unsigned short* bcan = (unsigned short*)(ws + OFF_BCAN);
    unsigned short* qkv  = (unsigned short*)(ws + OFF_QKV);

    probe_kernel<<<dim3(1), dim3(64), 0, stream>>>((const unsigned int*)d_in[0], flag);

    convert_kernel<<<dim3(2048), dim3(256), 0, stream>>>(d_in[0], xcan, TOKENS * DM, flag);
    convert_kernel<<<dim3(32), dim3(256), 0, stream>>>(d_in[1], wcan + 0 * DM * DM, DM * DM, flag);
    convert_kernel<<<dim3(32), dim3(256), 0, stream>>>(d_in[3], wcan + 1 * DM * DM, DM * DM, flag);
    convert_kernel<<<dim3(32), dim3(256), 0, stream>>>(d_in[5], wcan + 2 * DM * DM, DM * DM, flag);
    convert_kernel<<<dim3(1), dim3(64), 0, stream>>>(d_in[2], bcan + 0 * DM, DM, flag);
    convert_kernel<<<dim3(1), dim3(64), 0, stream>>>(d_in[4], bcan + 1 * DM, DM, flag);
    convert_kernel<<<dim3(1), dim3(64), 0, stream>>>(d_in[6], bcan + 2 * DM, DM, flag);

    pewb_kernel<<<dim3(66), dim3(256), 0, stream>>>(wcan, bcan, pewb);
    qkv_gemm<<<dim3(TOKENS / BM, NOUT / BN), dim3(256), 0, stream>>>(xcan, wcan, pewb, qkv);
    attn_kernel<<<dim3(TOKENS / JOINTS), dim3(256), 0, stream>>>(qkv, d_out, flag);
}

// Round 5
// 319.874 us; speedup vs baseline: 1.2575x; 1.2575x over previous
//
#include <hip/hip_runtime.h>

#define TOKENS 90112
#define DM 256
#define NOUT 768
#define JOINTS 22

typedef __attribute__((ext_vector_type(8))) short bf16x8;
typedef __attribute__((ext_vector_type(4))) float f32x4;

__device__ __forceinline__ float b2f(unsigned short u) {
    union { unsigned int i; float f; } x; x.i = ((unsigned int)u) << 16; return x.f;
}
__device__ __forceinline__ unsigned short f2b(float f) {
    union { float f; unsigned int u; } x; x.f = f;
    unsigned int r = x.u + 0x7FFFu + ((x.u >> 16) & 1u);
    return (unsigned short)(r >> 16);
}

// ws layout
#define OFF_PEWB 0
#define OFF_WCAN (JOINTS * NOUT * 4)                 // 67584
#define OFF_QKV  (OFF_WCAN + 3 * DM * DM * 2)        // 460800

// ---------------- convert W (fp32 -> bf16), 3 matrices ----------------
__global__ __launch_bounds__(256) void wconv_kernel(const float* __restrict__ w0,
                                                    const float* __restrict__ w1,
                                                    const float* __restrict__ w2,
                                                    unsigned short* __restrict__ wcan)
{
    const float* w = (blockIdx.y == 0) ? w0 : (blockIdx.y == 1 ? w1 : w2);
    int i = (blockIdx.x * 256 + threadIdx.x) * 8;
    const float* s = w + i;
    union { uint4 v; float f[4]; } a, b;
    a.v = *(const uint4*)(s);
    b.v = *(const uint4*)(s + 4);
    union { uint4 v; unsigned short u[8]; } o;
    #pragma unroll
    for (int k = 0; k < 4; ++k) { o.u[k] = f2b(a.f[k]); o.u[4 + k] = f2b(b.f[k]); }
    *(uint4*)(wcan + blockIdx.y * (DM * DM) + i) = o.v;
}

// ---------------- PEWB[j,e] = bias[e] + sum_d pe[j,d] * W[e,d]  (fp32 inputs) ----------------
__global__ __launch_bounds__(256) void pewb_kernel(const float* __restrict__ wq,
                                                   const float* __restrict__ wk,
                                                   const float* __restrict__ wv,
                                                   const float* __restrict__ bq,
                                                   const float* __restrict__ bk,
                                                   const float* __restrict__ bv,
                                                   float* __restrict__ pewb)
{
    __shared__ float pe_s[DM];
    const int j   = blockIdx.x / 3;
    const int mat = blockIdx.x % 3;
    const int t = threadIdx.x;
    {
        int i = t >> 1;
        float div = __expf((float)(2 * i) * (-9.210340371976184f / 256.0f)); // -ln(10000)/256
        float ang = (float)j * div;
        pe_s[t] = (t & 1) ? cosf(ang) : sinf(ang);
    }
    __syncthreads();
    const float* w  = (mat == 0) ? wq : (mat == 1 ? wk : wv);
    const float* bb = (mat == 0) ? bq : (mat == 1 ? bk : bv);
    float acc = bb[t];
    const float* wr = w + (size_t)t * DM;
    #pragma unroll 8
    for (int d = 0; d < DM; ++d) acc += pe_s[d] * wr[d];
    pewb[j * NOUT + mat * DM + t] = acc;
}

// ---------------- QKV GEMM: x(fp32) read once, full-K A-tile, inner n-loop ----------------
#define BM 64
#define BN 128

__global__ __launch_bounds__(256) void qkv_gemm(const float* __restrict__ x,
                                                const unsigned short* __restrict__ wcan,
                                                const float* __restrict__ pewb,
                                                unsigned short* __restrict__ qkv)
{
    // As: 64 rows x 256 cols bf16, chunk-swizzled: chunk c stored at (c&24)|((c&7)^(row&7))
    // Bs: 128 rows x 64 cols bf16, chunk-swizzled: chunk c stored at c^(row&7)
    __shared__ __align__(16) unsigned short As[BM * 256];   // 32 KB
    __shared__ __align__(16) unsigned short Bs[BN * 64];    // 16 KB

    const int t    = threadIdx.x;
    const int m0   = blockIdx.x * BM;
    const int lane = t & 63;
    const int wave = t >> 6;
    const int wm   = (wave & 1) * 32;
    const int wn   = (wave >> 1) * 64;
    const int lrow = lane & 15;
    const int quad = lane >> 4;

    // stage full-K x tile, converting fp32 -> bf16 (8 chunks of 8 per thread)
    #pragma unroll
    for (int i = 0; i < 8; ++i) {
        int ch  = t + i * 256;          // 0..2047
        int row = ch >> 5, c = ch & 31;
        const float* src = x + (size_t)(m0 + row) * DM + c * 8;
        union { uint4 v; float f[4]; } a, b;
        a.v = *(const uint4*)(src);
        b.v = *(const uint4*)(src + 4);
        union { uint4 v; unsigned short u[8]; } o;
        #pragma unroll
        for (int k = 0; k < 4; ++k) { o.u[k] = f2b(a.f[k]); o.u[4 + k] = f2b(b.f[k]); }
        int cs = (c & 24) | ((c & 7) ^ (row & 7));
        *(uint4*)(&As[row * 256 + cs * 8]) = o.v;
    }

    for (int bn = 0; bn < 6; ++bn) {
        const unsigned short* wbase = wcan + (bn >> 1) * (DM * DM) + (bn & 1) * (BN * DM);

        f32x4 acc[2][4];
        #pragma unroll
        for (int mi = 0; mi < 2; ++mi)
            #pragma unroll
            for (int ni = 0; ni < 4; ++ni)
                acc[mi][ni] = (f32x4){0.f, 0.f, 0.f, 0.f};

        for (int k0 = 0; k0 < DM; k0 += 64) {
            __syncthreads();   // Bs readers done (and As staged, first iter)
            #pragma unroll
            for (int i = 0; i < 4; ++i) {
                int ch  = t + i * 256;      // 0..1023
                int row = ch >> 3, c = ch & 7;
                uint4 v = *(const uint4*)(&wbase[(size_t)row * DM + k0 + c * 8]);
                *(uint4*)(&Bs[row * 64 + ((c ^ (row & 7)) * 8)]) = v;
            }
            __syncthreads();
            #pragma unroll
            for (int kk = 0; kk < 64; kk += 32) {
                bf16x8 a[2], b[4];
                #pragma unroll
                for (int mi = 0; mi < 2; ++mi) {
                    int row = wm + mi * 16 + lrow;
                    int c   = ((k0 + kk) >> 3) + quad;
                    int cs  = (c & 24) | ((c & 7) ^ (row & 7));
                    a[mi] = *(const bf16x8*)(&As[row * 256 + cs * 8]);
                }
                #pragma unroll
                for (int ni = 0; ni < 4; ++ni) {
                    int row = wn + ni * 16 + lrow;
                    int c   = (kk >> 3) + quad;
                    b[ni] = *(const bf16x8*)(&Bs[row * 64 + ((c ^ (row & 7)) * 8)]);
                }
                #pragma unroll
                for (int mi = 0; mi < 2; ++mi)
                    #pragma unroll
                    for (int ni = 0; ni < 4; ++ni)
                        acc[mi][ni] = __builtin_amdgcn_mfma_f32_16x16x32_bf16(
                            a[mi], b[ni], acc[mi][ni], 0, 0, 0);
            }
        }

        // epilogue: add PEWB[joint], store bf16
        const int n0 = bn * BN;
        #pragma unroll
        for (int mi = 0; mi < 2; ++mi) {
            #pragma unroll
            for (int r = 0; r < 4; ++r) {
                int row   = wm + mi * 16 + quad * 4 + r;   // C row = (lane>>4)*4 + reg
                int token = m0 + row;
                int joint = token % JOINTS;
                const float* pw = pewb + joint * NOUT + n0;
                size_t obase = (size_t)token * NOUT + n0;
                #pragma unroll
                for (int ni = 0; ni < 4; ++ni) {
                    int col = wn + ni * 16 + lrow;         // C col = lane&15
                    qkv[obase + col] = f2b(acc[mi][ni][r] + pw[col]);
                }
            }
        }
    }
}

// ---------------- block-diagonal attention, one block per (batch, frame) ----------------
#define KVSTR 712           // shorts per head (22*32 + 8 pad)
#define OSTR 260            // floats per O row (256 + 4 pad)

__global__ __launch_bounds__(256) void attn_kernel(const unsigned short* __restrict__ qkv,
                                                   float* __restrict__ out)
{
    __shared__ __align__(16) char smem_raw[JOINTS * OSTR * 4];  // 22880 B (>= 2*8*KVSTR*2 = 22784)
    unsigned short* kv  = (unsigned short*)smem_raw;
    float*          o_s = (float*)smem_raw;

    const int t  = threadIdx.x;
    const int tb = blockIdx.x * JOINTS;

    // stage K,V as bf16: 22 rows x 64 chunks (e in [256,768))
    for (int i = t; i < JOINTS * 64; i += 256) {
        int j  = i >> 6;
        int cc = i & 63;
        int e  = 256 + cc * 8;
        int mat = e >> 8;            // 1=K, 2=V
        int h  = (e >> 5) & 7;
        int d0 = e & 31;
        uint4 v = *(const uint4*)(&qkv[(size_t)(tb + j) * NOUT + e]);
        *(uint4*)(&kv[(mat - 1) * (8 * KVSTR) + h * KVSTR + j * 32 + d0]) = v;
    }
    __syncthreads();

    const bool active = (t < 176);
    float o[32];
    if (active) {
        const int h  = t / 22;
        const int qi = t - h * 22;
        const int token = tb + qi;

        float q[32];
        {
            const unsigned short* qg = qkv + (size_t)token * NOUT + h * 32;
            #pragma unroll
            for (int c4 = 0; c4 < 4; ++c4) {
                union { uint4 v; unsigned short u[8]; } r;
                r.v = *(const uint4*)(qg + c4 * 8);
                #pragma unroll
                for (int ii = 0; ii < 8; ++ii)
                    q[c4 * 8 + ii] = b2f(r.u[ii]) * 0.17677669529663688f; // 1/sqrt(32)
            }
        }
        const unsigned short* kh = kv + h * KVSTR;
        const unsigned short* vh = kv + 8 * KVSTR + h * KVSTR;

        float sc[22];
        float mx = -3.0e38f;
        #pragma unroll
        for (int j = 0; j < 22; ++j) {
            const unsigned short* kr = kh + j * 32;
            float s = 0.f;
            #pragma unroll
            for (int d = 0; d < 32; ++d) s += q[d] * b2f(kr[d]);
            sc[j] = s;
            mx = fmaxf(mx, s);
        }
        float sum = 0.f;
        #pragma unroll
        for (int j = 0; j < 22; ++j) { sc[j] = __expf(sc[j] - mx); sum += sc[j]; }
        float inv = 1.f / sum;

        #pragma unroll
        for (int d = 0; d < 32; ++d) o[d] = 0.f;
        #pragma unroll
        for (int j = 0; j < 22; ++j) {
            float p = sc[j] * inv;
            const unsigned short* vr = vh + j * 32;
            #pragma unroll
            for (int d = 0; d < 32; ++d) o[d] += p * b2f(vr[d]);
        }
    }
    __syncthreads();   // all K/V reads done before o_s overwrites the union

    if (active) {
        const int h  = t / 22;
        const int qi = t - h * 22;
        float* od = o_s + qi * OSTR + h * 32;
        #pragma unroll
        for (int k = 0; k < 8; ++k)
            *(float4*)(od + k * 4) = make_float4(o[k * 4], o[k * 4 + 1], o[k * 4 + 2], o[k * 4 + 3]);
    }
    __syncthreads();

    // cooperative coalesced store: frame's 22x256 fp32 rows are contiguous in out
    float* gbase = out + (size_t)tb * DM;
    for (int i4 = t; i4 < JOINTS * 64; i4 += 256) {
        int row = i4 >> 6;
        int col = (i4 & 63) * 4;
        *(float4*)(gbase + i4 * 4) = *(const float4*)(o_s + row * OSTR + col);
    }
}

extern "C" void kernel_launch(void* const* d_in, const int* in_sizes, int n_in,
                              void* d_out, int out_size, void* d_ws, size_t ws_size,
                              hipStream_t stream) {
    const float* x  = (const float*)d_in[0];
    const float* wq = (const float*)d_in[1];
    const float* bq = (const float*)d_in[2];
    const float* wk = (const float*)d_in[3];
    const float* bk = (const float*)d_in[4];
    const float* wv = (const float*)d_in[5];
    const float* bv = (const float*)d_in[6];

    char* ws = (char*)d_ws;
    float*          pewb = (float*)(ws + OFF_PEWB);
    unsigned short* wcan = (unsigned short*)(ws + OFF_WCAN);
    unsigned short* qkv  = (unsigned short*)(ws + OFF_QKV);

    wconv_kernel<<<dim3(32, 3), dim3(256), 0, stream>>>(wq, wk, wv, wcan);
    pewb_kernel<<<dim3(66), dim3(256), 0, stream>>>(wq, wk, wv, bq, bk, bv, pewb);
    qkv_gemm<<<dim3(TOKENS / BM), dim3(256), 0, stream>>>(x, wcan, pewb, qkv);
    attn_kernel<<<dim3(TOKENS / JOINTS), dim3(256), 0, stream>>>(qkv, (float*)d_out);
}